// Round 5
// baseline (594.703 us; speedup 1.0000x reference)
//
#include <hip/hip_runtime.h>
#include <hip/hip_bf16.h>
#include <hip/hip_fp16.h>

typedef _Float16 v2h __attribute__((ext_vector_type(2)));
typedef _Float16 v8h __attribute__((ext_vector_type(8)));
typedef __fp16  v2hf __attribute__((ext_vector_type(2)));
typedef float v4f __attribute__((ext_vector_type(4)));

static inline __device__ float leaky(float v) { return v >= 0.f ? v : 0.01f * v; }

static inline __device__ v2h pkrtz(float a, float b) {
    v2hf r = __builtin_amdgcn_cvt_pkrtz(a, b);
    return __builtin_bit_cast(v2h, r);
}

// ---------------- workspace layout ----------------
// f32 region (element offsets from ws):
#define W4S_OFF   0          // 110592 (padded conv4 weights [oc64][ic48][9][4])
#define H3_OFF    1655808    // 196608
#define FEAT_OFF  1852416    // 32768
#define M_OFF     1885184    // 65536
#define OT_OFF    1950720    // 4096
// f16 region starts at f32 offset 1954816 (byte 7819264):
#define F16_BASE  1954816
#define WL1_OFF   0          // 4608   conv1 B-frags [kstep9][lane64][8]
#define BF2_OFF   4608       // 76800  conv2 B-frags [nt2][kstep75][lane64][8]
#define BF3_OFF   81408      // 192000 conv3 B-frags [nt3][tap125][lane64][8]
#define H2C_OFF   273408     // 5619712 h2 channels-last [m175616][oc32]
#define H1C_OFF   5893120    // NB*1362944

// ---------------- weight prep ----------------
__global__ void prep_kernel(const float* __restrict__ w1, const float* __restrict__ w2,
                            const float* __restrict__ w3, const float* __restrict__ w4,
                            float* __restrict__ w4s, _Float16* __restrict__ Bw1,
                            _Float16* __restrict__ Bf2, _Float16* __restrict__ Bf3) {
    int i = blockIdx.x * 256 + threadIdx.x;
    if (i < 4608) {
        // conv1 B-frag: kstep ks (9), lane l, elem j. oc = l&15, kgroup = l>>4.
        // group g = ks*4+kg -> (kz,ky); j = kx (0..7, taps 6,7 are zero pad)
        int ks = i >> 9, l = (i >> 3) & 63, j = i & 7;
        int oc = l & 15, kg = l >> 4;
        int g = ks * 4 + kg;
        int kz = g / 6, ky = g % 6;
        Bw1[i] = (j < 6) ? (_Float16)w1[oc * 216 + kz * 36 + ky * 6 + j]
                         : (_Float16)0.f;
    } else if (i < 4608 + 76800) {
        int j2 = i - 4608;
        int nt = j2 / 38400, r = j2 % 38400;
        int t = r / 512, l = (r % 512) >> 3, j = r & 7;
        int oc = nt * 16 + (l & 15);
        int k = (l >> 4) * 8 + j;
        int kz = t / 15, ky = (t % 15) / 3, kxp = t % 3;
        int kx = kxp * 2 + (k >= 16 ? 1 : 0);
        int ic = k & 15;
        Bf2[j2] = (kx < 5) ? (_Float16)w2[oc * 2000 + ic * 125 + kz * 25 + ky * 5 + kx]
                           : (_Float16)0.f;
    } else if (i < 4608 + 76800 + 192000) {
        int j3 = i - (4608 + 76800);
        int nt = j3 / 64000, r = j3 % 64000;
        int tap = r / 512, l = (r % 512) >> 3, j = r & 7;
        int oc = nt * 16 + (l & 15);
        int ic = (l >> 4) * 8 + j;
        Bf3[j3] = (_Float16)w3[oc * 4000 + ic * 125 + tap];
    } else {
        int j4 = i - (4608 + 76800 + 192000);
        if (j4 < 110592) {
            // w4s[oc][ic][r9][4]: padded rows for aligned float4 loads in conv4
            int kx = j4 & 3, r = (j4 >> 2) % 9, ic = (j4 >> 2) / 9 % 48, oc = j4 / 1728;
            w4s[j4] = (kx < 3) ? w4[oc * 1296 + ic * 27 + r * 3 + kx] : 0.f;
        }
    }
}

// ---------------- conv1: persistent double-buffered MFMA implicit GEMM, 8 waves ----------------
// x[64,92^3] f32 -> h1c[nb][z44][y44][x44][oc16] f16, k=6, s=2
// Grid: 512 persistent blocks x 512 threads (2 blocks/CU, 16 waves/CU, 2x27KB LDS).
// Each block grid-strides over tiles (nb, zq, yt); per tile: issue next-tile loads ->
// compute current tile -> convert+write next buffer -> one barrier.
// Wave wv: z = zq*4+(wv&3), y-half = wv>>2 (2 y each); 3 x-tiles (bases 0,16,28).
__global__ __launch_bounds__(512, 4) void conv1_kernel(
    const float* __restrict__ x, const _Float16* __restrict__ Bw1,
    const float* __restrict__ b1, _Float16* __restrict__ h1c, int n0, int NT) {
    __shared__ __align__(16) _Float16 buf[2][13824];  // 2 x (144 rows x 96 f16)
    int tid = threadIdx.x;
    int lane = tid & 63, wv = tid >> 6;   // wv 0..7
    int col = lane & 15, kg = lane >> 4;
    int zl = wv & 3, yh = wv >> 2;

    int t0 = blockIdx.x;
    if (t0 >= NT) return;

    // per-thread staging constants (tid-derived, constant across tiles)
    int D_[7], W_[7];
    bool act_[7];
#pragma unroll
    for (int i = 0; i < 7; i++) {
        int u = tid + i * 512;
        act_[i] = (u < 3312);
        int uu = act_[i] ? u : 0;
        int row = uu / 23, c = uu % 23;
        D_[i] = (row / 12) * 8464 + (row % 12) * 92 + 4 * c;  // f32 elems in x
        W_[i] = row * 96 + 4 * c;                             // f16 elems in buf
    }

    // preload all 9 B-fragments into VGPRs
    v8h Bv[9];
#pragma unroll
    for (int ks = 0; ks < 9; ks++) Bv[ks] = *(const v8h*)(Bw1 + ks * 512 + lane * 8);
    // per-kstep LDS row offset (bytes): group g = ks*4+kg -> (kz,ky)
    int offs[9];
#pragma unroll
    for (int ks = 0; ks < 9; ks++) {
        int g = ks * 4 + kg;
        offs[ks] = ((g / 6) * 12 + (g % 6)) * 192;
    }
    float bias = b1[col];

    // zero row pads (f16 92..95) once for both buffers; staging never writes them
    if (tid < 144) {
        uint2 zz; zz.x = 0u; zz.y = 0u;
        *(uint2*)(&buf[0][tid * 96 + 92]) = zz;
        *(uint2*)(&buf[1][tid * 96 + 92]) = zz;
    }

    // prologue: stage tile t0 into buf[0]
    {
        int nb = t0 / 121, rr = t0 % 121;
        const float* bp = x + (long)(n0 + nb) * 778688 + (rr / 11) * 8 * 8464 + (rr % 11) * 8 * 92;
        float4 ld[7];
#pragma unroll
        for (int i = 0; i < 7; i++) if (act_[i]) ld[i] = *(const float4*)(bp + D_[i]);
#pragma unroll
        for (int i = 0; i < 7; i++) if (act_[i]) {
            union { v2h h[2]; uint2 u2; } pk;
            pk.h[0] = pkrtz(ld[i].x, ld[i].y);
            pk.h[1] = pkrtz(ld[i].z, ld[i].w);
            *(uint2*)(&buf[0][W_[i]]) = pk.u2;
        }
    }
    __syncthreads();

    int cur = 0;
    int stride = gridDim.x;
    for (int t = t0; t < NT; t += stride) {
        int tn = t + stride;
        bool hn = tn < NT;
        float4 ld[7];
        if (hn) {
            int nb = tn / 121, rr = tn % 121;
            const float* bp = x + (long)(n0 + nb) * 778688 + (rr / 11) * 8 * 8464 + (rr % 11) * 8 * 92;
#pragma unroll
            for (int i = 0; i < 7; i++) if (act_[i]) ld[i] = *(const float4*)(bp + D_[i]);
        }
        __builtin_amdgcn_sched_barrier(0);  // loads issued before compute begins

        // compute tile t from buf[cur]
        {
            int nb = t / 121, rr = t % 121;
            int zq = rr / 11, yt = rr % 11;
            const uint* lds32 = (const uint*)&buf[cur][0];
            int z = zq * 4 + zl;
#pragma unroll
            for (int yy = 0; yy < 2; yy++) {
                int yl = yh * 2 + yy;
#pragma unroll
                for (int xt = 0; xt < 3; xt++) {
                    int xo_base = (xt == 2) ? 28 : (xt << 4);
                    int base_byte = (24 * zl + 2 * yl) * 192 + (xo_base + col) * 4;
                    v4f acc = {0.f, 0.f, 0.f, 0.f};
#pragma unroll
                    for (int ks = 0; ks < 9; ks++) {
                        int di = (base_byte + offs[ks]) >> 2;
                        union { uint u[4]; v8h h; } A;
                        A.u[0] = lds32[di + 0];
                        A.u[1] = lds32[di + 1];
                        A.u[2] = lds32[di + 2];
                        A.u[3] = lds32[di + 3];
                        acc = __builtin_amdgcn_mfma_f32_16x16x32_f16(A.h, Bv[ks], acc, 0, 0, 0);
                    }
                    int y = yt * 4 + yl;
                    long obase = ((long)((nb * 44 + z) * 44 + y) * 44 + xo_base + kg * 4) * 16 + col;
#pragma unroll
                    for (int reg = 0; reg < 4; reg++) {
                        h1c[obase + reg * 16] = (_Float16)leaky(acc[reg] + bias);
                    }
                }
            }
        }

        // convert + write next tile into the other buffer
        if (hn) {
            _Float16* wb = &buf[cur ^ 1][0];
#pragma unroll
            for (int i = 0; i < 7; i++) if (act_[i]) {
                union { v2h h[2]; uint2 u2; } pk;
                pk.h[0] = pkrtz(ld[i].x, ld[i].y);
                pk.h[1] = pkrtz(ld[i].z, ld[i].w);
                *(uint2*)(wb + W_[i]) = pk.u2;
            }
        }
        __syncthreads();
        cur ^= 1;
    }
}

// ---------------- conv2: MFMA implicit GEMM, 2 M-tiles/wave, XCD-chunked ----------------
// h1c[nb][iz][iy][ix][ic16] f16 -> h2c[m][oc32] f16, k=5, s=3
// wave: 2 M-tiles (16 pos each) x 32 oc; K = 150 padded taps x 16 ic, 75 ksteps.
// Grid 1372 blocks (5.4/CU) for latency hiding; bijective XCD swizzle for L2 reuse.
__global__ __launch_bounds__(256) void conv2_kernel(
    const _Float16* __restrict__ h1c, const _Float16* __restrict__ Bf2,
    const float* __restrict__ b2, _Float16* __restrict__ h2c, int n0, int mlimit) {
    int tid = threadIdx.x;
    int lane = tid & 63, wv = tid >> 6;
    int nwg = gridDim.x;
    int orig = blockIdx.x;
    int xcd = orig & 7, lid = orig >> 3;
    int q = nwg >> 3, r = nwg & 7;
    int swz = (xcd < r ? xcd * (q + 1) : r * (q + 1) + (xcd - r) * q) + lid;
    int t0 = (swz * 4 + wv) * 2;
    int col = lane & 15, kgrp = lane >> 4;
    int par = kgrp >> 1, ico = (kgrp & 1) * 8;

    int base[2];
    bool valid[2];
#pragma unroll
    for (int i = 0; i < 2; i++) {
        int m = (t0 + i) * 16 + col;
        valid[i] = m < mlimit;
        int mm = valid[i] ? m : 0;
        int nl = mm / 2744, rm = mm % 2744;
        int z = rm / 196; rm %= 196;
        int y = rm / 14, xx = rm % 14;
        base[i] = nl * 1362944 + z * 3 * 30976 + y * 3 * 704 + xx * 3 * 16 + ico + par * 16;
    }

    v4f acc[2][2];
#pragma unroll
    for (int i = 0; i < 2; i++)
#pragma unroll
        for (int nt = 0; nt < 2; nt++) acc[i][nt] = (v4f){0.f, 0.f, 0.f, 0.f};

    int t = 0;
    for (int kz = 0; kz < 5; kz++) {
        for (int ky = 0; ky < 5; ky++) {
#pragma unroll
            for (int kxp = 0; kxp < 3; kxp++, t++) {
                int d = kz * 30976 + ky * 704 + kxp * 32;
                v8h B0 = *(const v8h*)(Bf2 + t * 512 + lane * 8);
                v8h B1 = *(const v8h*)(Bf2 + (75 + t) * 512 + lane * 8);
                v8h A0 = *(const v8h*)(h1c + base[0] + d);
                v8h A1 = *(const v8h*)(h1c + base[1] + d);
                acc[0][0] = __builtin_amdgcn_mfma_f32_16x16x32_f16(A0, B0, acc[0][0], 0, 0, 0);
                acc[0][1] = __builtin_amdgcn_mfma_f32_16x16x32_f16(A0, B1, acc[0][1], 0, 0, 0);
                acc[1][0] = __builtin_amdgcn_mfma_f32_16x16x32_f16(A1, B0, acc[1][0], 0, 0, 0);
                acc[1][1] = __builtin_amdgcn_mfma_f32_16x16x32_f16(A1, B1, acc[1][1], 0, 0, 0);
            }
        }
    }

#pragma unroll
    for (int i = 0; i < 2; i++) {
        if (!valid[i]) continue;
#pragma unroll
        for (int nt = 0; nt < 2; nt++) {
            int oc = nt * 16 + col;
            float bb = b2[oc];
#pragma unroll
            for (int reg = 0; reg < 4; reg++) {
                int mlocal = (t0 + i) * 16 + kgrp * 4 + reg;
                float vv = leaky(acc[i][nt][reg] + bb);
                h2c[(long)(n0 * 2744 + mlocal) * 32 + oc] = (_Float16)vv;
            }
        }
    }
}

// ---------------- conv3: MFMA implicit GEMM, fused K-split (8 waves) + combine ----------------
// h2c[m2744n][ic32] f16 -> h3[n][oc48][pos64] f32, k=5, s=3.
// Block = one m-tile (16 pos); 8 waves split the 125 taps (16 each); LDS reduce;
// wave 0 applies bias+leaky and writes h3 directly.
__global__ __launch_bounds__(512) void conv3_kernel(
    const _Float16* __restrict__ h2c, const _Float16* __restrict__ Bf3,
    const float* __restrict__ b3, float* __restrict__ h3) {
    __shared__ float part[7][64][13];
    int tid = threadIdx.x;
    int lane = tid & 63, wv = tid >> 6;   // wv 0..7
    int mt = blockIdx.x;                  // 0..255
    int col = lane & 15, kgrp = lane >> 4;
    int m = mt * 16 + col;
    int n = m >> 6, pos = m & 63;
    int z = pos >> 4, y = (pos >> 2) & 3, xx = pos & 3;
    int base = (n * 2744 + z * 3 * 196 + y * 3 * 14 + xx * 3) * 32 + kgrp * 8;

    v4f acc[3];
#pragma unroll
    for (int nt = 0; nt < 3; nt++) acc[nt] = (v4f){0.f, 0.f, 0.f, 0.f};

    int tap0 = wv * 16;
    int tap1 = tap0 + 16 < 125 ? tap0 + 16 : 125;
    for (int tap = tap0; tap < tap1; tap++) {
        int kz = tap / 25, rr = tap % 25, ky = rr / 5, kx = rr % 5;
        int d = (kz * 196 + ky * 14 + kx) * 32;
        v8h A  = *(const v8h*)(h2c + base + d);
        v8h B0 = *(const v8h*)(Bf3 + tap * 512 + lane * 8);
        v8h B1 = *(const v8h*)(Bf3 + (125 + tap) * 512 + lane * 8);
        v8h B2 = *(const v8h*)(Bf3 + (250 + tap) * 512 + lane * 8);
        acc[0] = __builtin_amdgcn_mfma_f32_16x16x32_f16(A, B0, acc[0], 0, 0, 0);
        acc[1] = __builtin_amdgcn_mfma_f32_16x16x32_f16(A, B1, acc[1], 0, 0, 0);
        acc[2] = __builtin_amdgcn_mfma_f32_16x16x32_f16(A, B2, acc[2], 0, 0, 0);
    }

    if (wv > 0) {
#pragma unroll
        for (int nt = 0; nt < 3; nt++)
#pragma unroll
            for (int reg = 0; reg < 4; reg++)
                part[wv - 1][lane][nt * 4 + reg] = acc[nt][reg];
    }
    __syncthreads();
    if (wv == 0) {
#pragma unroll
        for (int w = 0; w < 7; w++)
#pragma unroll
            for (int nt = 0; nt < 3; nt++)
#pragma unroll
                for (int reg = 0; reg < 4; reg++)
                    acc[nt][reg] += part[w][lane][nt * 4 + reg];
#pragma unroll
        for (int nt = 0; nt < 3; nt++) {
            int oc = nt * 16 + col;
            float bb = b3[oc];
#pragma unroll
            for (int reg = 0; reg < 4; reg++) {
                int md = mt * 16 + kgrp * 4 + reg;
                h3[((md >> 6) * 48 + oc) * 64 + (md & 63)] = leaky(acc[nt][reg] + bb);
            }
        }
    }
}

// conv4: h3[64,48,4,4,4] f32 -> feat[64,512], k=3, s=1; vectorized float4 loads
__global__ void conv4_kernel(const float* __restrict__ h3, const float* __restrict__ w4s,
                             const float* __restrict__ b4, float* __restrict__ feat) {
    int o = blockIdx.x * 64 + threadIdx.x;  // 32768 = 512*64
    int pos = o & 7;
    int oc  = (o >> 3) & 63;
    int n   = o >> 9;
    int px = pos & 1, py = (pos >> 1) & 1, pz = pos >> 2;
    const float* xn = h3 + (long)n * 48 * 64;
    const float4* wp = (const float4*)(w4s + oc * 1728);  // [ic48][r9][4]
    float acc = 0.f;
    for (int ic = 0; ic < 48; ic++) {
        const float* xc = xn + ic * 64;
#pragma unroll
        for (int kz = 0; kz < 3; kz++)
#pragma unroll
            for (int ky = 0; ky < 3; ky++) {
                float4 xq = *(const float4*)(xc + (pz + kz) * 16 + (py + ky) * 4);
                float4 wq = wp[ic * 9 + kz * 3 + ky];
                float a0 = px ? xq.y : xq.x;
                float a1 = px ? xq.z : xq.y;
                float a2 = px ? xq.w : xq.z;
                acc += a0 * wq.x + a1 * wq.y + a2 * wq.z;
            }
    }
    feat[o] = leaky(acc + b4[oc]);  // o == n*512 + oc*8 + pos
}

// M[64,1024] = feat[64,512] @ T[512,1024]
__global__ void m_kernel(const float* __restrict__ feat, const float* __restrict__ T,
                         float* __restrict__ M) {
    int o = blockIdx.x * 256 + threadIdx.x;  // 65536 = 256*256
    int col = o & 1023;
    int n   = o >> 10;
    const float* fr = feat + n * 512;
    float acc = 0.f;
#pragma unroll 4
    for (int f = 0; f < 512; f++) acc += fr[f] * T[f * 1024 + col];
    M[o] = acc;
}

// out_T[i,k] = sum_j exp( sum_l |M[i,k,l]-M[j,k,l]| )
// grid: 64 blocks (one per i), 256 threads = 64 k x 4 j-quarters
__global__ void outt_kernel(const float* __restrict__ M, float* __restrict__ oT) {
    __shared__ float part[3][64];
    int i = blockIdx.x;
    int tid = threadIdx.x;
    int k = tid & 63, jq = tid >> 6;
    float mi[16];
    const float4* Mi = (const float4*)(M + i * 1024 + k * 16);
#pragma unroll
    for (int q = 0; q < 4; q++) {
        float4 a = Mi[q];
        mi[q*4+0] = a.x; mi[q*4+1] = a.y; mi[q*4+2] = a.z; mi[q*4+3] = a.w;
    }
    float s = 0.f;
    for (int j = jq * 16; j < jq * 16 + 16; j++) {
        const float4* Mj = (const float4*)(M + j * 1024 + k * 16);
        float d = 0.f;
#pragma unroll
        for (int q = 0; q < 4; q++) {
            float4 a = Mj[q];
            d += fabsf(mi[q*4+0]-a.x) + fabsf(mi[q*4+1]-a.y) + fabsf(mi[q*4+2]-a.z) + fabsf(mi[q*4+3]-a.w);
        }
        s += __expf(d);
    }
    if (jq > 0) part[jq - 1][k] = s;
    __syncthreads();
    if (jq == 0) {
        s += part[0][k] + part[1][k] + part[2][k];
        oT[i * 64 + k] = s;
    }
}

// out[i] = sigmoid( feat[i,:].Wm[0:512] + oT[i,:].Wm[512:576] + bm )
__global__ void final_kernel(const float* __restrict__ feat, const float* __restrict__ oT,
                             const float* __restrict__ Wm, const float* __restrict__ bm,
                             float* __restrict__ out) {
    int i = blockIdx.x;      // 64 outputs
    int lane = threadIdx.x;  // 64 lanes
    const float* fr = feat + i * 512;
    float z = 0.f;
#pragma unroll
    for (int q = 0; q < 8; q++) z += fr[lane + q * 64] * Wm[lane + q * 64];
    z += oT[i * 64 + lane] * Wm[512 + lane];
#pragma unroll
    for (int off = 32; off > 0; off >>= 1) z += __shfl_down(z, off);
    if (lane == 0) out[i] = 1.f / (1.f + __expf(-(z + bm[0])));
}

extern "C" void kernel_launch(void* const* d_in, const int* in_sizes, int n_in,
                              void* d_out, int out_size, void* d_ws, size_t ws_size,
                              hipStream_t stream) {
    const float* x  = (const float*)d_in[0];
    const float* w1 = (const float*)d_in[1];
    const float* b1 = (const float*)d_in[2];
    const float* w2 = (const float*)d_in[3];
    const float* b2 = (const float*)d_in[4];
    const float* w3 = (const float*)d_in[5];
    const float* b3 = (const float*)d_in[6];
    const float* w4 = (const float*)d_in[7];
    const float* b4 = (const float*)d_in[8];
    const float* T  = (const float*)d_in[9];
    const float* Wm = (const float*)d_in[10];
    const float* bm = (const float*)d_in[11];

    float* ws   = (float*)d_ws;
    float* w4s  = ws + W4S_OFF;
    float* h3   = ws + H3_OFF;
    float* feat = ws + FEAT_OFF;
    float* Mb   = ws + M_OFF;
    float* oT   = ws + OT_OFF;
    _Float16* f16b = (_Float16*)(ws + F16_BASE);
    _Float16* Bw1  = f16b + WL1_OFF;
    _Float16* Bf2  = f16b + BF2_OFF;
    _Float16* Bf3  = f16b + BF3_OFF;
    _Float16* h2c  = f16b + H2C_OFF;
    _Float16* h1c  = f16b + H1C_OFF;

    // 4608 + 76800 + 192000 + 110592 = 384000 = 1500 * 256
    prep_kernel<<<1500, 256, 0, stream>>>(w1, w2, w3, w4, w4s, Bw1, Bf2, Bf3);

    // choose batch-group size by workspace capacity
    size_t fixed_bytes = (size_t)F16_BASE * 4 + (size_t)H1C_OFF * 2;
    int NB;
    if (ws_size >= fixed_bytes + (64ll * 1362944 + 64) * 2) NB = 64;
    else if (ws_size >= fixed_bytes + (16ll * 1362944 + 64) * 2) NB = 16;
    else NB = 8;

    for (int n0 = 0; n0 < 64; n0 += NB) {
        conv1_kernel<<<512, 512, 0, stream>>>(x, Bw1, b1, h1c, n0, NB * 121);
        int mlimit = NB * 2744;
        int blocks2 = (mlimit + 127) / 128;  // 2 tiles x 16 pos x 4 waves
        conv2_kernel<<<blocks2, 256, 0, stream>>>(h1c, Bf2, b2, h2c, n0, mlimit);
    }
    conv3_kernel<<<256, 512, 0, stream>>>(h2c, Bf3, b3, h3);
    conv4_kernel<<<512, 64, 0, stream>>>(h3, w4s, b4, feat);
    m_kernel<<<256, 256, 0, stream>>>(feat, T, Mb);
    outt_kernel<<<64, 256, 0, stream>>>(Mb, oT);
    final_kernel<<<64, 64, 0, stream>>>(feat, oT, Wm, bm, (float*)d_out);
}

// Round 6
// 568.728 us; speedup vs baseline: 1.0457x; 1.0457x over previous
//
#include <hip/hip_runtime.h>
#include <hip/hip_bf16.h>
#include <hip/hip_fp16.h>

typedef _Float16 v2h __attribute__((ext_vector_type(2)));
typedef _Float16 v8h __attribute__((ext_vector_type(8)));
typedef __fp16  v2hf __attribute__((ext_vector_type(2)));
typedef float v4f __attribute__((ext_vector_type(4)));

static inline __device__ float leaky(float v) { return v >= 0.f ? v : 0.01f * v; }

static inline __device__ v2h pkrtz(float a, float b) {
    v2hf r = __builtin_amdgcn_cvt_pkrtz(a, b);
    return __builtin_bit_cast(v2h, r);
}

// ---------------- workspace layout ----------------
// f32 region (element offsets from ws):
#define W4S_OFF   0          // 110592 (padded conv4 weights [oc64][ic48][9][4])
#define H3_OFF    1655808    // 196608
#define FEAT_OFF  1852416    // 32768
#define M_OFF     1885184    // 65536
#define OT_OFF    1950720    // 4096
// f16 region starts at f32 offset 1954816 (byte 7819264):
#define F16_BASE  1954816
#define WL1_OFF   0          // 4608   conv1 B-frags [kstep9][lane64][8]
#define BF2_OFF   4608       // 76800  conv2 B-frags [nt2][kstep75][lane64][8]
#define BF3_OFF   81408      // 192000 conv3 B-frags [nt3][tap125][lane64][8]
#define H2C_OFF   273408     // 5619712 h2 channels-last [m175616][oc32]
#define H1C_OFF   5893120    // NB*1362944

// ---------------- weight prep ----------------
__global__ void prep_kernel(const float* __restrict__ w1, const float* __restrict__ w2,
                            const float* __restrict__ w3, const float* __restrict__ w4,
                            float* __restrict__ w4s, _Float16* __restrict__ Bw1,
                            _Float16* __restrict__ Bf2, _Float16* __restrict__ Bf3) {
    int i = blockIdx.x * 256 + threadIdx.x;
    if (i < 4608) {
        // conv1 B-frag: kstep ks (9), lane l, elem j. oc = l&15, kgroup = l>>4.
        // group g = ks*4+kg -> (kz,ky); j = kx (0..7, taps 6,7 are zero pad)
        int ks = i >> 9, l = (i >> 3) & 63, j = i & 7;
        int oc = l & 15, kg = l >> 4;
        int g = ks * 4 + kg;
        int kz = g / 6, ky = g % 6;
        Bw1[i] = (j < 6) ? (_Float16)w1[oc * 216 + kz * 36 + ky * 6 + j]
                         : (_Float16)0.f;
    } else if (i < 4608 + 76800) {
        int j2 = i - 4608;
        int nt = j2 / 38400, r = j2 % 38400;
        int t = r / 512, l = (r % 512) >> 3, j = r & 7;
        int oc = nt * 16 + (l & 15);
        int k = (l >> 4) * 8 + j;
        int kz = t / 15, ky = (t % 15) / 3, kxp = t % 3;
        int kx = kxp * 2 + (k >= 16 ? 1 : 0);
        int ic = k & 15;
        Bf2[j2] = (kx < 5) ? (_Float16)w2[oc * 2000 + ic * 125 + kz * 25 + ky * 5 + kx]
                           : (_Float16)0.f;
    } else if (i < 4608 + 76800 + 192000) {
        int j3 = i - (4608 + 76800);
        int nt = j3 / 64000, r = j3 % 64000;
        int tap = r / 512, l = (r % 512) >> 3, j = r & 7;
        int oc = nt * 16 + (l & 15);
        int ic = (l >> 4) * 8 + j;
        Bf3[j3] = (_Float16)w3[oc * 4000 + ic * 125 + tap];
    } else {
        int j4 = i - (4608 + 76800 + 192000);
        if (j4 < 110592) {
            // w4s[oc][ic][r9][4]: padded rows for aligned float4 loads in conv4
            int kx = j4 & 3, r = (j4 >> 2) % 9, ic = (j4 >> 2) / 9 % 48, oc = j4 / 1728;
            w4s[j4] = (kx < 3) ? w4[oc * 1296 + ic * 27 + r * 3 + kx] : 0.f;
        }
    }
}

// ---------------- conv1: persistent double-buffered MFMA implicit GEMM, 8 waves ----------------
// x[64,92^3] f32 -> h1c[nb][z44][y44][x44][oc16] f16, k=6, s=2
// Grid: 512 persistent blocks x 512 threads (2 blocks/CU, 16 waves/CU, 2x27KB LDS).
__global__ __launch_bounds__(512, 4) void conv1_kernel(
    const float* __restrict__ x, const _Float16* __restrict__ Bw1,
    const float* __restrict__ b1, _Float16* __restrict__ h1c, int n0, int NT) {
    __shared__ __align__(16) _Float16 buf[2][13824];  // 2 x (144 rows x 96 f16)
    int tid = threadIdx.x;
    int lane = tid & 63, wv = tid >> 6;   // wv 0..7
    int col = lane & 15, kg = lane >> 4;
    int zl = wv & 3, yh = wv >> 2;

    int t0 = blockIdx.x;
    if (t0 >= NT) return;

    // per-thread staging constants (tid-derived, constant across tiles)
    int D_[7], W_[7];
    bool act_[7];
#pragma unroll
    for (int i = 0; i < 7; i++) {
        int u = tid + i * 512;
        act_[i] = (u < 3312);
        int uu = act_[i] ? u : 0;
        int row = uu / 23, c = uu % 23;
        D_[i] = (row / 12) * 8464 + (row % 12) * 92 + 4 * c;  // f32 elems in x
        W_[i] = row * 96 + 4 * c;                             // f16 elems in buf
    }

    // preload all 9 B-fragments into VGPRs
    v8h Bv[9];
#pragma unroll
    for (int ks = 0; ks < 9; ks++) Bv[ks] = *(const v8h*)(Bw1 + ks * 512 + lane * 8);
    // per-kstep LDS row offset (bytes): group g = ks*4+kg -> (kz,ky)
    int offs[9];
#pragma unroll
    for (int ks = 0; ks < 9; ks++) {
        int g = ks * 4 + kg;
        offs[ks] = ((g / 6) * 12 + (g % 6)) * 192;
    }
    float bias = b1[col];

    // zero row pads (f16 92..95) once for both buffers; staging never writes them
    if (tid < 144) {
        uint2 zz; zz.x = 0u; zz.y = 0u;
        *(uint2*)(&buf[0][tid * 96 + 92]) = zz;
        *(uint2*)(&buf[1][tid * 96 + 92]) = zz;
    }

    // prologue: stage tile t0 into buf[0]
    {
        int nb = t0 / 121, rr = t0 % 121;
        const float* bp = x + (long)(n0 + nb) * 778688 + (rr / 11) * 8 * 8464 + (rr % 11) * 8 * 92;
        float4 ld[7];
#pragma unroll
        for (int i = 0; i < 7; i++) if (act_[i]) ld[i] = *(const float4*)(bp + D_[i]);
#pragma unroll
        for (int i = 0; i < 7; i++) if (act_[i]) {
            union { v2h h[2]; uint2 u2; } pk;
            pk.h[0] = pkrtz(ld[i].x, ld[i].y);
            pk.h[1] = pkrtz(ld[i].z, ld[i].w);
            *(uint2*)(&buf[0][W_[i]]) = pk.u2;
        }
    }
    __syncthreads();

    int cur = 0;
    int stride = gridDim.x;
    for (int t = t0; t < NT; t += stride) {
        int tn = t + stride;
        bool hn = tn < NT;
        float4 ld[7];
        if (hn) {
            int nb = tn / 121, rr = tn % 121;
            const float* bp = x + (long)(n0 + nb) * 778688 + (rr / 11) * 8 * 8464 + (rr % 11) * 8 * 92;
#pragma unroll
            for (int i = 0; i < 7; i++) if (act_[i]) ld[i] = *(const float4*)(bp + D_[i]);
        }
        __builtin_amdgcn_sched_barrier(0);  // loads issued before compute begins

        // compute tile t from buf[cur]
        {
            int nb = t / 121, rr = t % 121;
            int zq = rr / 11, yt = rr % 11;
            const uint* lds32 = (const uint*)&buf[cur][0];
            int z = zq * 4 + zl;
#pragma unroll
            for (int yy = 0; yy < 2; yy++) {
                int yl = yh * 2 + yy;
#pragma unroll
                for (int xt = 0; xt < 3; xt++) {
                    int xo_base = (xt == 2) ? 28 : (xt << 4);
                    int base_byte = (24 * zl + 2 * yl) * 192 + (xo_base + col) * 4;
                    v4f acc = {0.f, 0.f, 0.f, 0.f};
#pragma unroll
                    for (int ks = 0; ks < 9; ks++) {
                        int di = (base_byte + offs[ks]) >> 2;
                        union { uint u[4]; v8h h; } A;
                        A.u[0] = lds32[di + 0];
                        A.u[1] = lds32[di + 1];
                        A.u[2] = lds32[di + 2];
                        A.u[3] = lds32[di + 3];
                        acc = __builtin_amdgcn_mfma_f32_16x16x32_f16(A.h, Bv[ks], acc, 0, 0, 0);
                    }
                    int y = yt * 4 + yl;
                    long obase = ((long)((nb * 44 + z) * 44 + y) * 44 + xo_base + kg * 4) * 16 + col;
#pragma unroll
                    for (int reg = 0; reg < 4; reg++) {
                        h1c[obase + reg * 16] = (_Float16)leaky(acc[reg] + bias);
                    }
                }
            }
        }

        // convert + write next tile into the other buffer
        if (hn) {
            _Float16* wb = &buf[cur ^ 1][0];
#pragma unroll
            for (int i = 0; i < 7; i++) if (act_[i]) {
                union { v2h h[2]; uint2 u2; } pk;
                pk.h[0] = pkrtz(ld[i].x, ld[i].y);
                pk.h[1] = pkrtz(ld[i].z, ld[i].w);
                *(uint2*)(wb + W_[i]) = pk.u2;
            }
        }
        __syncthreads();
        cur ^= 1;
    }
}

// ---------------- conv2: LDS-plane-staged MFMA implicit GEMM ----------------
// h1c[nb][iz][iy][ix][ic16] f16 -> h2c[m][oc32] f16, k=5, s=3
// Block = one (nb, z-out): loops kz=0..4 staging input plane iz=3z+kz
// (44x44x16 f16 = 62KB, contiguous -> coalesced copy) into LDS; 8 waves cover the
// 13 M-tiles (196 out pos) x 32 oc; 15 (ky,kxp)-ksteps per plane; acc across kz
// in registers. 2 blocks/CU (LDS), 16 waves/CU. XCD-chunked: same-XCD blocks get
// consecutive z -> adjacent blocks share 2 of 5 planes in L2.
__global__ __launch_bounds__(512, 4) void conv2_kernel(
    const _Float16* __restrict__ h1c, const _Float16* __restrict__ Bf2,
    const float* __restrict__ b2, _Float16* __restrict__ h2c, int n0) {
    __shared__ __align__(16) _Float16 plane[30976 + 64];  // +64 zero pad (kx=5 taps)
    int tid = threadIdx.x;
    int lane = tid & 63, wv = tid >> 6;   // wv 0..7
    int nwg = gridDim.x;
    int orig = blockIdx.x;
    int xcd = orig & 7, lid = orig >> 3;
    int q = nwg >> 3, r = nwg & 7;
    int swz = (xcd < r ? xcd * (q + 1) : r * (q + 1) + (xcd - r) * q) + lid;
    int nbL = swz / 14, z = swz % 14;

    int col = lane & 15, kgrp = lane >> 4;
    int par = kgrp >> 1, ico = (kgrp & 1) * 8;

    // wave -> M-tiles: waves 0..4 take 2 tiles, waves 5..7 take 1 (13 tiles total)
    int mts[2]; int nmt;
    if (wv < 5) { mts[0] = 2 * wv; mts[1] = 2 * wv + 1; nmt = 2; }
    else        { mts[0] = 5 + wv; mts[1] = 0;          nmt = 1; }

    // per-tile A base inside plane (f16 elems); clamp pad lanes to a valid pos
    int ab[2];
#pragma unroll
    for (int it = 0; it < 2; it++) {
        int pa = mts[it] * 16 + col; if (pa > 195) pa = 195;
        int y = pa / 14, xx = pa % 14;
        ab[it] = (3 * y) * 704 + (3 * xx + par) * 16 + ico;
    }

    v4f acc[2][2];
#pragma unroll
    for (int it = 0; it < 2; it++)
#pragma unroll
        for (int nt = 0; nt < 2; nt++) acc[it][nt] = (v4f){0.f, 0.f, 0.f, 0.f};

    // zero the pad tail so kx=5 (zero-weight) reads never see NaN bits
    if (tid < 8) { uint4 zz; zz.x = zz.y = zz.z = zz.w = 0u; ((uint4*)(plane + 30976))[tid] = zz; }

    const uint4* srcb = (const uint4*)(h1c + (long)nbL * 1362944);
    uint4* dst = (uint4*)plane;

    for (int kz = 0; kz < 5; kz++) {
        int iz = 3 * z + kz;
        const uint4* src = srcb + iz * 3872;  // 30976 f16 = 3872 uint4 per plane
        for (int u = tid; u < 3872; u += 512) dst[u] = src[u];
        __syncthreads();

        int tb = kz * 15;
#pragma unroll
        for (int ky = 0; ky < 5; ky++) {
#pragma unroll
            for (int kxp = 0; kxp < 3; kxp++) {
                int t = tb + ky * 3 + kxp;
                v8h B0 = *(const v8h*)(Bf2 + t * 512 + lane * 8);
                v8h B1 = *(const v8h*)(Bf2 + (75 + t) * 512 + lane * 8);
                int d = ky * 704 + kxp * 32;
                v8h A0 = *(const v8h*)(plane + ab[0] + d);
                acc[0][0] = __builtin_amdgcn_mfma_f32_16x16x32_f16(A0, B0, acc[0][0], 0, 0, 0);
                acc[0][1] = __builtin_amdgcn_mfma_f32_16x16x32_f16(A0, B1, acc[0][1], 0, 0, 0);
                if (nmt == 2) {
                    v8h A1 = *(const v8h*)(plane + ab[1] + d);
                    acc[1][0] = __builtin_amdgcn_mfma_f32_16x16x32_f16(A1, B0, acc[1][0], 0, 0, 0);
                    acc[1][1] = __builtin_amdgcn_mfma_f32_16x16x32_f16(A1, B1, acc[1][1], 0, 0, 0);
                }
            }
        }
        __syncthreads();
    }

#pragma unroll
    for (int it = 0; it < 2; it++) {
        if (it >= nmt) break;
#pragma unroll
        for (int nt = 0; nt < 2; nt++) {
            int oc = nt * 16 + col;
            float bb = b2[oc];
#pragma unroll
            for (int reg = 0; reg < 4; reg++) {
                int pc = mts[it] * 16 + kgrp * 4 + reg;
                if (pc < 196) {
                    long mg = (long)(n0 + nbL) * 2744 + z * 196 + pc;
                    h2c[mg * 32 + oc] = (_Float16)leaky(acc[it][nt][reg] + bb);
                }
            }
        }
    }
}

// ---------------- conv3: MFMA implicit GEMM, fused K-split (8 waves) + combine ----------------
// h2c[m2744n][ic32] f16 -> h3[n][oc48][pos64] f32, k=5, s=3.
__global__ __launch_bounds__(512) void conv3_kernel(
    const _Float16* __restrict__ h2c, const _Float16* __restrict__ Bf3,
    const float* __restrict__ b3, float* __restrict__ h3) {
    __shared__ float part[7][64][13];
    int tid = threadIdx.x;
    int lane = tid & 63, wv = tid >> 6;   // wv 0..7
    int mt = blockIdx.x;                  // 0..255
    int col = lane & 15, kgrp = lane >> 4;
    int m = mt * 16 + col;
    int n = m >> 6, pos = m & 63;
    int z = pos >> 4, y = (pos >> 2) & 3, xx = pos & 3;
    int base = (n * 2744 + z * 3 * 196 + y * 3 * 14 + xx * 3) * 32 + kgrp * 8;

    v4f acc[3];
#pragma unroll
    for (int nt = 0; nt < 3; nt++) acc[nt] = (v4f){0.f, 0.f, 0.f, 0.f};

    int tap0 = wv * 16;
    int tap1 = tap0 + 16 < 125 ? tap0 + 16 : 125;
    for (int tap = tap0; tap < tap1; tap++) {
        int kz = tap / 25, rr = tap % 25, ky = rr / 5, kx = rr % 5;
        int d = (kz * 196 + ky * 14 + kx) * 32;
        v8h A  = *(const v8h*)(h2c + base + d);
        v8h B0 = *(const v8h*)(Bf3 + tap * 512 + lane * 8);
        v8h B1 = *(const v8h*)(Bf3 + (125 + tap) * 512 + lane * 8);
        v8h B2 = *(const v8h*)(Bf3 + (250 + tap) * 512 + lane * 8);
        acc[0] = __builtin_amdgcn_mfma_f32_16x16x32_f16(A, B0, acc[0], 0, 0, 0);
        acc[1] = __builtin_amdgcn_mfma_f32_16x16x32_f16(A, B1, acc[1], 0, 0, 0);
        acc[2] = __builtin_amdgcn_mfma_f32_16x16x32_f16(A, B2, acc[2], 0, 0, 0);
    }

    if (wv > 0) {
#pragma unroll
        for (int nt = 0; nt < 3; nt++)
#pragma unroll
            for (int reg = 0; reg < 4; reg++)
                part[wv - 1][lane][nt * 4 + reg] = acc[nt][reg];
    }
    __syncthreads();
    if (wv == 0) {
#pragma unroll
        for (int w = 0; w < 7; w++)
#pragma unroll
            for (int nt = 0; nt < 3; nt++)
#pragma unroll
                for (int reg = 0; reg < 4; reg++)
                    acc[nt][reg] += part[w][lane][nt * 4 + reg];
#pragma unroll
        for (int nt = 0; nt < 3; nt++) {
            int oc = nt * 16 + col;
            float bb = b3[oc];
#pragma unroll
            for (int reg = 0; reg < 4; reg++) {
                int md = mt * 16 + kgrp * 4 + reg;
                h3[((md >> 6) * 48 + oc) * 64 + (md & 63)] = leaky(acc[nt][reg] + bb);
            }
        }
    }
}

// conv4: h3[64,48,4,4,4] f32 -> feat[64,512], k=3, s=1; vectorized float4 loads
__global__ void conv4_kernel(const float* __restrict__ h3, const float* __restrict__ w4s,
                             const float* __restrict__ b4, float* __restrict__ feat) {
    int o = blockIdx.x * 64 + threadIdx.x;  // 32768 = 512*64
    int pos = o & 7;
    int oc  = (o >> 3) & 63;
    int n   = o >> 9;
    int px = pos & 1, py = (pos >> 1) & 1, pz = pos >> 2;
    const float* xn = h3 + (long)n * 48 * 64;
    const float4* wp = (const float4*)(w4s + oc * 1728);  // [ic48][r9][4]
    float acc = 0.f;
    for (int ic = 0; ic < 48; ic++) {
        const float* xc = xn + ic * 64;
#pragma unroll
        for (int kz = 0; kz < 3; kz++)
#pragma unroll
            for (int ky = 0; ky < 3; ky++) {
                float4 xq = *(const float4*)(xc + (pz + kz) * 16 + (py + ky) * 4);
                float4 wq = wp[ic * 9 + kz * 3 + ky];
                float a0 = px ? xq.y : xq.x;
                float a1 = px ? xq.z : xq.y;
                float a2 = px ? xq.w : xq.z;
                acc += a0 * wq.x + a1 * wq.y + a2 * wq.z;
            }
    }
    feat[o] = leaky(acc + b4[oc]);  // o == n*512 + oc*8 + pos
}

// M[64,1024] = feat[64,512] @ T[512,1024]
__global__ void m_kernel(const float* __restrict__ feat, const float* __restrict__ T,
                         float* __restrict__ M) {
    int o = blockIdx.x * 256 + threadIdx.x;  // 65536 = 256*256
    int col = o & 1023;
    int n   = o >> 10;
    const float* fr = feat + n * 512;
    float acc = 0.f;
#pragma unroll 4
    for (int f = 0; f < 512; f++) acc += fr[f] * T[f * 1024 + col];
    M[o] = acc;
}

// out_T[i,k] = sum_j exp( sum_l |M[i,k,l]-M[j,k,l]| )
// grid: 64 blocks (one per i), 256 threads = 64 k x 4 j-quarters
__global__ void outt_kernel(const float* __restrict__ M, float* __restrict__ oT) {
    __shared__ float part[3][64];
    int i = blockIdx.x;
    int tid = threadIdx.x;
    int k = tid & 63, jq = tid >> 6;
    float mi[16];
    const float4* Mi = (const float4*)(M + i * 1024 + k * 16);
#pragma unroll
    for (int q = 0; q < 4; q++) {
        float4 a = Mi[q];
        mi[q*4+0] = a.x; mi[q*4+1] = a.y; mi[q*4+2] = a.z; mi[q*4+3] = a.w;
    }
    float s = 0.f;
    for (int j = jq * 16; j < jq * 16 + 16; j++) {
        const float4* Mj = (const float4*)(M + j * 1024 + k * 16);
        float d = 0.f;
#pragma unroll
        for (int q = 0; q < 4; q++) {
            float4 a = Mj[q];
            d += fabsf(mi[q*4+0]-a.x) + fabsf(mi[q*4+1]-a.y) + fabsf(mi[q*4+2]-a.z) + fabsf(mi[q*4+3]-a.w);
        }
        s += __expf(d);
    }
    if (jq > 0) part[jq - 1][k] = s;
    __syncthreads();
    if (jq == 0) {
        s += part[0][k] + part[1][k] + part[2][k];
        oT[i * 64 + k] = s;
    }
}

// out[i] = sigmoid( feat[i,:].Wm[0:512] + oT[i,:].Wm[512:576] + bm )
__global__ void final_kernel(const float* __restrict__ feat, const float* __restrict__ oT,
                             const float* __restrict__ Wm, const float* __restrict__ bm,
                             float* __restrict__ out) {
    int i = blockIdx.x;      // 64 outputs
    int lane = threadIdx.x;  // 64 lanes
    const float* fr = feat + i * 512;
    float z = 0.f;
#pragma unroll
    for (int q = 0; q < 8; q++) z += fr[lane + q * 64] * Wm[lane + q * 64];
    z += oT[i * 64 + lane] * Wm[512 + lane];
#pragma unroll
    for (int off = 32; off > 0; off >>= 1) z += __shfl_down(z, off);
    if (lane == 0) out[i] = 1.f / (1.f + __expf(-(z + bm[0])));
}

extern "C" void kernel_launch(void* const* d_in, const int* in_sizes, int n_in,
                              void* d_out, int out_size, void* d_ws, size_t ws_size,
                              hipStream_t stream) {
    const float* x  = (const float*)d_in[0];
    const float* w1 = (const float*)d_in[1];
    const float* b1 = (const float*)d_in[2];
    const float* w2 = (const float*)d_in[3];
    const float* b2 = (const float*)d_in[4];
    const float* w3 = (const float*)d_in[5];
    const float* b3 = (const float*)d_in[6];
    const float* w4 = (const float*)d_in[7];
    const float* b4 = (const float*)d_in[8];
    const float* T  = (const float*)d_in[9];
    const float* Wm = (const float*)d_in[10];
    const float* bm = (const float*)d_in[11];

    float* ws   = (float*)d_ws;
    float* w4s  = ws + W4S_OFF;
    float* h3   = ws + H3_OFF;
    float* feat = ws + FEAT_OFF;
    float* Mb   = ws + M_OFF;
    float* oT   = ws + OT_OFF;
    _Float16* f16b = (_Float16*)(ws + F16_BASE);
    _Float16* Bw1  = f16b + WL1_OFF;
    _Float16* Bf2  = f16b + BF2_OFF;
    _Float16* Bf3  = f16b + BF3_OFF;
    _Float16* h2c  = f16b + H2C_OFF;
    _Float16* h1c  = f16b + H1C_OFF;

    // 4608 + 76800 + 192000 + 110592 = 384000 = 1500 * 256
    prep_kernel<<<1500, 256, 0, stream>>>(w1, w2, w3, w4, w4s, Bw1, Bf2, Bf3);

    // choose batch-group size by workspace capacity
    size_t fixed_bytes = (size_t)F16_BASE * 4 + (size_t)H1C_OFF * 2;
    int NB;
    if (ws_size >= fixed_bytes + (64ll * 1362944 + 64) * 2) NB = 64;
    else if (ws_size >= fixed_bytes + (16ll * 1362944 + 64) * 2) NB = 16;
    else NB = 8;

    for (int n0 = 0; n0 < 64; n0 += NB) {
        conv1_kernel<<<512, 512, 0, stream>>>(x, Bw1, b1, h1c, n0, NB * 121);
        conv2_kernel<<<NB * 14, 512, 0, stream>>>(h1c, Bf2, b2, h2c, n0);
    }
    conv3_kernel<<<256, 512, 0, stream>>>(h2c, Bf3, b3, h3);
    conv4_kernel<<<512, 64, 0, stream>>>(h3, w4s, b4, feat);
    m_kernel<<<256, 256, 0, stream>>>(feat, T, Mb);
    outt_kernel<<<64, 256, 0, stream>>>(Mb, oT);
    final_kernel<<<64, 64, 0, stream>>>(feat, oT, Wm, bm, (float*)d_out);
}